// Round 4
// baseline (485.809 us; speedup 1.0000x reference)
//
#include <hip/hip_runtime.h>
#include <hip/hip_bf16.h>
#include <cstdint>
#include <cstddef>

#define HH 1024
#define BB 8
#define TT 2048
#define MM (BB*TT)   // 16384
#define CC 64        // wkv chunks
#define LL (TT/CC)   // 32 steps per chunk

typedef __attribute__((ext_vector_type(8))) short bf16x8;
typedef __attribute__((ext_vector_type(16))) float f32x16;

__device__ __forceinline__ unsigned short f2bf(float f) {
  union { float f; unsigned u; } v; v.f = f;
  return (unsigned short)((v.u + 0x7fffu + ((v.u >> 16) & 1u)) >> 16);  // RNE
}
__device__ __forceinline__ float bf2f(unsigned short s) {
  union { float f; unsigned u; } v; v.u = ((unsigned)s) << 16;
  return v.f;
}

__device__ __forceinline__ void load_lds16(const void* g, void* l) {
  __builtin_amdgcn_global_load_lds((const __attribute__((address_space(1))) void*)g,
                                   (__attribute__((address_space(3))) void*)l,
                                   16, 0, 0);
}

// ---------------- weight fp32 -> bf16 ----------------
__global__ __launch_bounds__(256) void conv_w(const float* __restrict__ Wk,
    const float* __restrict__ Wv, const float* __restrict__ Wr,
    const float* __restrict__ Wo, unsigned short* __restrict__ dst) {
  const int i = (blockIdx.x * 256 + threadIdx.x) * 4;
  const float* src = blockIdx.y == 0 ? Wk : blockIdx.y == 1 ? Wv : blockIdx.y == 2 ? Wr : Wo;
  const float4 v = *(const float4*)(src + i);
  ushort4 o; o.x = f2bf(v.x); o.y = f2bf(v.y); o.z = f2bf(v.z); o.w = f2bf(v.w);
  *(ushort4*)(dst + (size_t)blockIdx.y * HH * HH + i) = o;
}

// ---------------- time-shift + mix -> bf16 kin/vin/rin ----------------
__global__ __launch_bounds__(256) void mix_kernel(const float* __restrict__ x,
    const float* __restrict__ tmk, const float* __restrict__ tmv, const float* __restrict__ tmr,
    unsigned short* __restrict__ kin, unsigned short* __restrict__ vin,
    unsigned short* __restrict__ rin) {
  const int gid = blockIdx.x * 256 + threadIdx.x;
  const size_t e0 = (size_t)gid * 4;
  const int h = (int)(e0 & (HH - 1));
  const int t = (int)((e0 >> 10) & (TT - 1));
  const float4 xv = *(const float4*)(x + e0);
  float4 sv = make_float4(0.f, 0.f, 0.f, 0.f);
  if (t != 0) sv = *(const float4*)(x + e0 - HH);
  const float4 k4 = *(const float4*)(tmk + h);
  const float4 v4 = *(const float4*)(tmv + h);
  const float4 r4 = *(const float4*)(tmr + h);
  ushort4 ko, vo, ro;
  ko.x = f2bf(sv.x + k4.x * (xv.x - sv.x)); ko.y = f2bf(sv.y + k4.y * (xv.y - sv.y));
  ko.z = f2bf(sv.z + k4.z * (xv.z - sv.z)); ko.w = f2bf(sv.w + k4.w * (xv.w - sv.w));
  vo.x = f2bf(sv.x + v4.x * (xv.x - sv.x)); vo.y = f2bf(sv.y + v4.y * (xv.y - sv.y));
  vo.z = f2bf(sv.z + v4.z * (xv.z - sv.z)); vo.w = f2bf(sv.w + v4.w * (xv.w - sv.w));
  ro.x = f2bf(sv.x + r4.x * (xv.x - sv.x)); ro.y = f2bf(sv.y + r4.y * (xv.y - sv.y));
  ro.z = f2bf(sv.z + r4.z * (xv.z - sv.z)); ro.w = f2bf(sv.w + r4.w * (xv.w - sv.w));
  *(ushort4*)(kin + e0) = ko;
  *(ushort4*)(vin + e0) = vo;
  *(ushort4*)(rin + e0) = ro;
}

// ---------------- GEMM core: C[128x128] tile, A[M,K]*B[N,K]^T, bf16 ----------------
// 4 waves in 2x2; each wave 64x64 = 2x2 tiles of 32x32, mfma_f32_32x32x16_bf16.
// LDS layout: k-major planes. Tile = 128 rows x 32 k = 512 chunks of 16B.
// chunk c -> (row = c & 127, plane q = c >> 7); LDS offset = (q*128 + row)*16B.
// Fragment reads are lane-sequential 16B chunks -> conflict-free.
__device__ __forceinline__ void gemm_core32(const unsigned short* __restrict__ Ag,
                                            const unsigned short* __restrict__ Bg,
                                            int m0, int n0,
                                            unsigned short* As, unsigned short* Bs,
                                            f32x16 acc[2][2]) {
  const int tid = threadIdx.x;
  const int lane = tid & 63;
  const int w = tid >> 6;
  const int K = HH;
  // staging: 2 issues/thread; c0 = tid (planes 0..1), c1 = 256+tid (planes 2..3)
  const int c0 = tid, c1 = 256 + tid;
  const unsigned short* ga0 = Ag + (size_t)(m0 + (c0 & 127)) * K + (c0 >> 7) * 8;
  const unsigned short* ga1 = Ag + (size_t)(m0 + (c1 & 127)) * K + (c1 >> 7) * 8;
  const unsigned short* gb0 = Bg + (size_t)(n0 + (c0 & 127)) * K + (c0 >> 7) * 8;
  const unsigned short* gb1 = Bg + (size_t)(n0 + (c1 & 127)) * K + (c1 >> 7) * 8;
  unsigned short* la0 = As + (size_t)w * 512;          // wave-uniform base (ushort units)
  unsigned short* la1 = As + 2048 + (size_t)w * 512;
  unsigned short* lb0 = Bs + (size_t)w * 512;
  unsigned short* lb1 = Bs + 2048 + (size_t)w * 512;
  const int wm = w >> 1, wn = w & 1;
  const int l31 = lane & 31, lh = lane >> 5;
  // frag addr (ushort units): plane kq*1024 + row*8
  const int arow0 = wm * 64 + l31;          // mi adds +32
  const int brow0 = wn * 64 + l31;          // nj adds +32

  for (int kt = 0; kt < K; kt += 32) {
    load_lds16(ga0 + kt, la0);
    load_lds16(ga1 + kt, la1);
    load_lds16(gb0 + kt, lb0);
    load_lds16(gb1 + kt, lb1);
    __syncthreads();
    bf16x8 af[2][2], bfr[2][2];
#pragma unroll
    for (int c = 0; c < 2; c++) {
      const int kq = c * 2 + lh;
#pragma unroll
      for (int mi = 0; mi < 2; mi++)
        af[mi][c] = *(const bf16x8*)(As + kq * 1024 + (arow0 + mi * 32) * 8);
#pragma unroll
      for (int nj = 0; nj < 2; nj++)
        bfr[nj][c] = *(const bf16x8*)(Bs + kq * 1024 + (brow0 + nj * 32) * 8);
    }
#pragma unroll
    for (int c = 0; c < 2; c++)
#pragma unroll
      for (int mi = 0; mi < 2; mi++)
#pragma unroll
        for (int nj = 0; nj < 2; nj++)
          acc[mi][nj] = __builtin_amdgcn_mfma_f32_32x32x16_bf16(af[mi][c], bfr[nj][c],
                                                                acc[mi][nj], 0, 0, 0);
    __syncthreads();
  }
}

// XCD-aware swizzle: x&7 -> xcd stripe of 16 m-tiles; n fast within stripe.
__device__ __forceinline__ void swizzle_mn(int x, int& m0, int& n0) {
  const int xcd = x & 7;
  const int t = x >> 3;
  const int bn = t & 7;
  const int bml = t >> 3;          // 0..15
  m0 = (xcd * 16 + bml) * 128;
  n0 = bn * 128;
}

// z=0: k -> bf16, z=1: v -> bf16, z=2: r -> sigmoid -> bf16
__global__ __launch_bounds__(256) void gemm_kvr(const unsigned short* __restrict__ kin,
    const unsigned short* __restrict__ vin, const unsigned short* __restrict__ rin,
    const unsigned short* __restrict__ Wbf,
    unsigned short* __restrict__ kb, unsigned short* __restrict__ vb,
    unsigned short* __restrict__ rb) {
  __shared__ unsigned short As[128 * 32];
  __shared__ unsigned short Bs[128 * 32];
  const int z = blockIdx.y;
  const unsigned short* Ag = z == 0 ? kin : (z == 1 ? vin : rin);
  const unsigned short* Bg = Wbf + (size_t)z * HH * HH;
  unsigned short* Cg = z == 0 ? kb : (z == 1 ? vb : rb);
  int m0, n0; swizzle_mn(blockIdx.x, m0, n0);
  f32x16 acc[2][2] = {};
  gemm_core32(Ag, Bg, m0, n0, As, Bs, acc);
  const int lane = threadIdx.x & 63, w = threadIdx.x >> 6;
  const int wm = w >> 1, wn = w & 1, l31 = lane & 31, lh = lane >> 5;
  const bool sig = (z == 2);
#pragma unroll
  for (int mi = 0; mi < 2; mi++)
#pragma unroll
    for (int nj = 0; nj < 2; nj++) {
      const int col = n0 + wn * 64 + nj * 32 + l31;
      const int rb0 = m0 + wm * 64 + mi * 32 + 4 * lh;
#pragma unroll
      for (int reg = 0; reg < 16; reg++) {
        const int row = rb0 + (reg & 3) + 8 * (reg >> 2);
        float vv = acc[mi][nj][reg];
        if (sig) vv = 1.0f / (1.0f + __expf(-vv));
        Cg[(size_t)row * HH + col] = f2bf(vv);
      }
    }
}

// out = rwkv @ Wo^T + bo  (fp32 out)
__global__ __launch_bounds__(256) void gemm_o(const unsigned short* __restrict__ Ag,
    const unsigned short* __restrict__ Bg, const float* __restrict__ bias,
    float* __restrict__ C) {
  __shared__ unsigned short As[128 * 32];
  __shared__ unsigned short Bs[128 * 32];
  int m0, n0; swizzle_mn(blockIdx.x, m0, n0);
  f32x16 acc[2][2] = {};
  gemm_core32(Ag, Bg, m0, n0, As, Bs, acc);
  const int lane = threadIdx.x & 63, w = threadIdx.x >> 6;
  const int wm = w >> 1, wn = w & 1, l31 = lane & 31, lh = lane >> 5;
#pragma unroll
  for (int mi = 0; mi < 2; mi++)
#pragma unroll
    for (int nj = 0; nj < 2; nj++) {
      const int col = n0 + wn * 64 + nj * 32 + l31;
      const float bv = bias[col];
      const int rb0 = m0 + wm * 64 + mi * 32 + 4 * lh;
#pragma unroll
      for (int reg = 0; reg < 16; reg++) {
        const int row = rb0 + (reg & 3) + 8 * (reg >> 2);
        C[(size_t)row * HH + col] = acc[mi][nj][reg] + bv;
      }
    }
}

// ---------------- WKV: chunk-parallel scan over T ----------------
__global__ __launch_bounds__(256) void wkv_part(const unsigned short* __restrict__ k,
    const unsigned short* __restrict__ v, const float* __restrict__ tdec,
    float* __restrict__ pnum, float* __restrict__ pden) {
  const int gid = blockIdx.x * 256 + threadIdx.x;   // 0 .. CC*BB*HH-1
  const int h = gid & (HH - 1);
  const int bh = gid & (BB * HH - 1);
  const int b = (gid >> 10) & (BB - 1);
  const int c = gid >> 13;
  const float td = __expf(-__expf(tdec[h]));
  size_t idx = (size_t)b * TT * HH + (size_t)(c * LL) * HH + h;
  float num = 0.f, den = 0.f;
#pragma unroll 8
  for (int i = 0; i < LL; ++i, idx += HH) {
    const float ek = __expf(bf2f(k[idx]));
    const float vt = bf2f(v[idx]);
    num = td * num + ek * vt;
    den = td * den + ek;
  }
  pnum[(size_t)c * (BB * HH) + bh] = num;
  pden[(size_t)c * (BB * HH) + bh] = den;
}

__global__ __launch_bounds__(256) void wkv_scan(const float* __restrict__ tdec,
    float* __restrict__ pnum, float* __restrict__ pden) {
  const int bh = blockIdx.x * 256 + threadIdx.x;     // 0..8191
  const int h = bh & (HH - 1);
  const float ed = __expf(tdec[h]);
  const float tdL = __expf(-ed * (float)LL);         // td^LL exactly
  float num = 0.f, den = 0.f;
#pragma unroll 8
  for (int c = 0; c < CC; ++c) {
    const size_t o = (size_t)c * (BB * HH) + bh;
    const float tn = pnum[o], td_ = pden[o];
    pnum[o] = num; pden[o] = den;
    num = tdL * num + tn;
    den = tdL * den + td_;
  }
}

__global__ __launch_bounds__(256) void wkv_final(const unsigned short* __restrict__ k,
    const unsigned short* __restrict__ v, const unsigned short* __restrict__ r,
    const float* __restrict__ tdec, const float* __restrict__ tfst,
    const float* __restrict__ pnum, const float* __restrict__ pden,
    unsigned short* __restrict__ rwkv) {
  const int gid = blockIdx.x * 256 + threadIdx.x;
  const int h = gid & (HH - 1);
  const int bh = gid & (BB * HH - 1);
  const int b = (gid >> 10) & (BB - 1);
  const int c = gid >> 13;
  const float td = __expf(-__expf(tdec[h]));
  const float etf = __expf(tfst[h]);
  float num = pnum[(size_t)c * (BB * HH) + bh];
  float den = pden[(size_t)c * (BB * HH) + bh];
  size_t idx = (size_t)b * TT * HH + (size_t)(c * LL) * HH + h;
#pragma unroll 4
  for (int i = 0; i < LL; ++i, idx += HH) {
    const float ek = __expf(bf2f(k[idx]));
    const float vt = bf2f(v[idx]);
    const float rt = bf2f(r[idx]);
    const float e = ek * etf;                        // exp(tf + k) = exp(k)*exp(tf)
    const float inv = __builtin_amdgcn_rcpf(den + e);
    const float outv = (num + e * vt) * inv;
    num = td * num + ek * vt;
    den = td * den + ek;
    rwkv[idx] = f2bf(outv * rt);
  }
}

extern "C" void kernel_launch(void* const* d_in, const int* in_sizes, int n_in,
                              void* d_out, int out_size, void* d_ws, size_t ws_size,
                              hipStream_t stream) {
  (void)in_sizes; (void)n_in; (void)out_size; (void)ws_size;
  const float* x    = (const float*)d_in[0];
  const float* tdec = (const float*)d_in[1];
  const float* tfst = (const float*)d_in[2];
  const float* tmk  = (const float*)d_in[3];
  const float* tmv  = (const float*)d_in[4];
  const float* tmr  = (const float*)d_in[5];
  const float* Wk   = (const float*)d_in[6];
  const float* Wv   = (const float*)d_in[7];
  const float* Wr   = (const float*)d_in[8];
  const float* Wo   = (const float*)d_in[9];
  const float* bo   = (const float*)d_in[10];
  float* out = (float*)d_out;

  char* ws = (char*)d_ws;
  const size_t MiB = (size_t)1 << 20;
  unsigned short* Wbf = (unsigned short*)(ws);             //   8 MiB
  unsigned short* kin = (unsigned short*)(ws + 8 * MiB);   //  32 MiB
  unsigned short* vin = (unsigned short*)(ws + 40 * MiB);  //  32 MiB
  unsigned short* rin = (unsigned short*)(ws + 72 * MiB);  //  32 MiB
  unsigned short* rb  = (unsigned short*)(ws + 104 * MiB); //  32 MiB  (peak 136 MiB)
  // k,v bf16 staged in d_out (64 MiB fp32 buffer = 2 x 32 MiB bf16); dead before gemm_o writes.
  unsigned short* kb = (unsigned short*)out;
  unsigned short* vb = kb + (size_t)MM * HH;
  unsigned short* rwkv = kin;                  // kin dead after gemm_kvr
  float* pnum = (float*)(ws + 40 * MiB);       // vin dead after gemm_kvr (2 MiB)
  float* pden = (float*)(ws + 42 * MiB);       // (2 MiB)

  hipLaunchKernelGGL(conv_w, dim3(1024, 4), dim3(256), 0, stream, Wk, Wv, Wr, Wo, Wbf);
  hipLaunchKernelGGL(mix_kernel, dim3(16384), dim3(256), 0, stream,
                     x, tmk, tmv, tmr, kin, vin, rin);
  hipLaunchKernelGGL(gemm_kvr, dim3(1024, 3), dim3(256), 0, stream,
                     kin, vin, rin, Wbf, kb, vb, rb);
  hipLaunchKernelGGL(wkv_part, dim3(2048), dim3(256), 0, stream,
                     kb, vb, tdec, pnum, pden);
  hipLaunchKernelGGL(wkv_scan, dim3(32), dim3(256), 0, stream,
                     tdec, pnum, pden);
  hipLaunchKernelGGL(wkv_final, dim3(2048), dim3(256), 0, stream,
                     kb, vb, rb, tdec, tfst, pnum, pden, rwkv);
  hipLaunchKernelGGL(gemm_o, dim3(1024), dim3(256), 0, stream,
                     rwkv, Wbf + (size_t)3 * HH * HH, bo, out);
}

// Round 5
// 383.610 us; speedup vs baseline: 1.2664x; 1.2664x over previous
//
#include <hip/hip_runtime.h>
#include <hip/hip_bf16.h>
#include <cstdint>
#include <cstddef>

#define HH 1024
#define BB 8
#define TT 2048
#define MM (BB*TT)   // 16384
#define CC 64        // wkv chunks
#define LL (TT/CC)   // 32 steps per chunk

typedef __attribute__((ext_vector_type(8))) short bf16x8;
typedef __attribute__((ext_vector_type(16))) float f32x16;

__device__ __forceinline__ unsigned short f2bf(float f) {
  union { float f; unsigned u; } v; v.f = f;
  return (unsigned short)((v.u + 0x7fffu + ((v.u >> 16) & 1u)) >> 16);  // RNE
}
__device__ __forceinline__ float bf2f(unsigned short s) {
  union { float f; unsigned u; } v; v.u = ((unsigned)s) << 16;
  return v.f;
}

__device__ __forceinline__ void load_lds16(const void* g, void* l) {
  __builtin_amdgcn_global_load_lds((const __attribute__((address_space(1))) void*)g,
                                   (__attribute__((address_space(3))) void*)l,
                                   16, 0, 0);
}

// ---------------- weight fp32 -> bf16 ----------------
__global__ __launch_bounds__(256) void conv_w(const float* __restrict__ Wk,
    const float* __restrict__ Wv, const float* __restrict__ Wr,
    const float* __restrict__ Wo, unsigned short* __restrict__ dst) {
  const int i = (blockIdx.x * 256 + threadIdx.x) * 4;
  const float* src = blockIdx.y == 0 ? Wk : blockIdx.y == 1 ? Wv : blockIdx.y == 2 ? Wr : Wo;
  const float4 v = *(const float4*)(src + i);
  ushort4 o; o.x = f2bf(v.x); o.y = f2bf(v.y); o.z = f2bf(v.z); o.w = f2bf(v.w);
  *(ushort4*)(dst + (size_t)blockIdx.y * HH * HH + i) = o;
}

// ---------------- time-shift + mix -> bf16 kin/vin/rin ----------------
__global__ __launch_bounds__(256) void mix_kernel(const float* __restrict__ x,
    const float* __restrict__ tmk, const float* __restrict__ tmv, const float* __restrict__ tmr,
    unsigned short* __restrict__ kin, unsigned short* __restrict__ vin,
    unsigned short* __restrict__ rin) {
  const int gid = blockIdx.x * 256 + threadIdx.x;
  const size_t e0 = (size_t)gid * 4;
  const int h = (int)(e0 & (HH - 1));
  const int t = (int)((e0 >> 10) & (TT - 1));
  const float4 xv = *(const float4*)(x + e0);
  float4 sv = make_float4(0.f, 0.f, 0.f, 0.f);
  if (t != 0) sv = *(const float4*)(x + e0 - HH);
  const float4 k4 = *(const float4*)(tmk + h);
  const float4 v4 = *(const float4*)(tmv + h);
  const float4 r4 = *(const float4*)(tmr + h);
  ushort4 ko, vo, ro;
  ko.x = f2bf(sv.x + k4.x * (xv.x - sv.x)); ko.y = f2bf(sv.y + k4.y * (xv.y - sv.y));
  ko.z = f2bf(sv.z + k4.z * (xv.z - sv.z)); ko.w = f2bf(sv.w + k4.w * (xv.w - sv.w));
  vo.x = f2bf(sv.x + v4.x * (xv.x - sv.x)); vo.y = f2bf(sv.y + v4.y * (xv.y - sv.y));
  vo.z = f2bf(sv.z + v4.z * (xv.z - sv.z)); vo.w = f2bf(sv.w + v4.w * (xv.w - sv.w));
  ro.x = f2bf(sv.x + r4.x * (xv.x - sv.x)); ro.y = f2bf(sv.y + r4.y * (xv.y - sv.y));
  ro.z = f2bf(sv.z + r4.z * (xv.z - sv.z)); ro.w = f2bf(sv.w + r4.w * (xv.w - sv.w));
  *(ushort4*)(kin + e0) = ko;
  *(ushort4*)(vin + e0) = vo;
  *(ushort4*)(rin + e0) = ro;
}

// ---------------- GEMM core: C[128x128] tile, A[M,K]*B[N,K]^T, bf16 ----------------
// 4 waves in 2x2; each wave 64x64 = 2x2 tiles of 32x32, mfma_f32_32x32x16_bf16.
// LDS layout: row-major (row r, slot s) at chunk c = r*4+s (16B chunks), holding
// global k-chunk q = s ^ ((r>>1)&3)  (XOR swizzle).
//  - staging: 4 consecutive lanes share a row, q's permute 0..3 -> coalesced 64B.
//  - frag read (r consecutive across lanes): bank = 16*(r&1) + 4*(kq^((r>>1)&3))
//    covers all 32 banks over 8 lanes -> conflict-free ds_read_b128.
__device__ __forceinline__ void gemm_core32(const unsigned short* __restrict__ Ag,
                                            const unsigned short* __restrict__ Bg,
                                            int m0, int n0,
                                            unsigned short* As, unsigned short* Bs,
                                            f32x16 acc[2][2]) {
  const int tid = threadIdx.x;
  const int lane = tid & 63;
  const int w = tid >> 6;
  const int K = HH;
  const int c0 = tid, c1 = 256 + tid;
  const int r0 = c0 >> 2, s0 = c0 & 3, q0 = s0 ^ ((r0 >> 1) & 3);
  const int r1 = c1 >> 2, s1 = c1 & 3, q1 = s1 ^ ((r1 >> 1) & 3);
  const unsigned short* ga0 = Ag + (size_t)(m0 + r0) * K + q0 * 8;
  const unsigned short* ga1 = Ag + (size_t)(m0 + r1) * K + q1 * 8;
  const unsigned short* gb0 = Bg + (size_t)(n0 + r0) * K + q0 * 8;
  const unsigned short* gb1 = Bg + (size_t)(n0 + r1) * K + q1 * 8;
  unsigned short* la0 = As + (size_t)w * 512;          // wave-uniform base (ushort units)
  unsigned short* la1 = As + 2048 + (size_t)w * 512;
  unsigned short* lb0 = Bs + (size_t)w * 512;
  unsigned short* lb1 = Bs + 2048 + (size_t)w * 512;
  const int wm = w >> 1, wn = w & 1;
  const int l31 = lane & 31, lh = lane >> 5;
  const int arow0 = wm * 64 + l31;          // mi adds +32
  const int brow0 = wn * 64 + l31;          // nj adds +32

  for (int kt = 0; kt < K; kt += 32) {
    load_lds16(ga0 + kt, la0);
    load_lds16(ga1 + kt, la1);
    load_lds16(gb0 + kt, lb0);
    load_lds16(gb1 + kt, lb1);
    __syncthreads();
    bf16x8 af[2][2], bfr[2][2];
#pragma unroll
    for (int c = 0; c < 2; c++) {
      const int kq = c * 2 + lh;
#pragma unroll
      for (int mi = 0; mi < 2; mi++) {
        const int ar = arow0 + mi * 32;
        af[mi][c] = *(const bf16x8*)(As + ar * 32 + (kq ^ ((ar >> 1) & 3)) * 8);
      }
#pragma unroll
      for (int nj = 0; nj < 2; nj++) {
        const int br = brow0 + nj * 32;
        bfr[nj][c] = *(const bf16x8*)(Bs + br * 32 + (kq ^ ((br >> 1) & 3)) * 8);
      }
    }
#pragma unroll
    for (int c = 0; c < 2; c++)
#pragma unroll
      for (int mi = 0; mi < 2; mi++)
#pragma unroll
        for (int nj = 0; nj < 2; nj++)
          acc[mi][nj] = __builtin_amdgcn_mfma_f32_32x32x16_bf16(af[mi][c], bfr[nj][c],
                                                                acc[mi][nj], 0, 0, 0);
    __syncthreads();
  }
}

// XCD-aware swizzle: x&7 -> xcd stripe of 16 m-tiles; n fast within stripe.
__device__ __forceinline__ void swizzle_mn(int x, int& m0, int& n0) {
  const int xcd = x & 7;
  const int t = x >> 3;
  const int bn = t & 7;
  const int bml = t >> 3;          // 0..15
  m0 = (xcd * 16 + bml) * 128;
  n0 = bn * 128;
}

// z=0: k -> bf16, z=1: v -> bf16, z=2: r -> sigmoid -> bf16
__global__ __launch_bounds__(256) void gemm_kvr(const unsigned short* __restrict__ kin,
    const unsigned short* __restrict__ vin, const unsigned short* __restrict__ rin,
    const unsigned short* __restrict__ Wbf,
    unsigned short* __restrict__ kb, unsigned short* __restrict__ vb,
    unsigned short* __restrict__ rb) {
  __shared__ unsigned short As[128 * 32];
  __shared__ unsigned short Bs[128 * 32];
  const int z = blockIdx.y;
  const unsigned short* Ag = z == 0 ? kin : (z == 1 ? vin : rin);
  const unsigned short* Bg = Wbf + (size_t)z * HH * HH;
  unsigned short* Cg = z == 0 ? kb : (z == 1 ? vb : rb);
  int m0, n0; swizzle_mn(blockIdx.x, m0, n0);
  f32x16 acc[2][2] = {};
  gemm_core32(Ag, Bg, m0, n0, As, Bs, acc);
  const int lane = threadIdx.x & 63, w = threadIdx.x >> 6;
  const int wm = w >> 1, wn = w & 1, l31 = lane & 31, lh = lane >> 5;
  const bool sig = (z == 2);
#pragma unroll
  for (int mi = 0; mi < 2; mi++)
#pragma unroll
    for (int nj = 0; nj < 2; nj++) {
      const int col = n0 + wn * 64 + nj * 32 + l31;
      const int rb0 = m0 + wm * 64 + mi * 32 + 4 * lh;
#pragma unroll
      for (int reg = 0; reg < 16; reg++) {
        const int row = rb0 + (reg & 3) + 8 * (reg >> 2);
        float vv = acc[mi][nj][reg];
        if (sig) vv = 1.0f / (1.0f + __expf(-vv));
        Cg[(size_t)row * HH + col] = f2bf(vv);
      }
    }
}

// out = rwkv @ Wo^T + bo  (fp32 out)
__global__ __launch_bounds__(256) void gemm_o(const unsigned short* __restrict__ Ag,
    const unsigned short* __restrict__ Bg, const float* __restrict__ bias,
    float* __restrict__ C) {
  __shared__ unsigned short As[128 * 32];
  __shared__ unsigned short Bs[128 * 32];
  int m0, n0; swizzle_mn(blockIdx.x, m0, n0);
  f32x16 acc[2][2] = {};
  gemm_core32(Ag, Bg, m0, n0, As, Bs, acc);
  const int lane = threadIdx.x & 63, w = threadIdx.x >> 6;
  const int wm = w >> 1, wn = w & 1, l31 = lane & 31, lh = lane >> 5;
#pragma unroll
  for (int mi = 0; mi < 2; mi++)
#pragma unroll
    for (int nj = 0; nj < 2; nj++) {
      const int col = n0 + wn * 64 + nj * 32 + l31;
      const float bv = bias[col];
      const int rb0 = m0 + wm * 64 + mi * 32 + 4 * lh;
#pragma unroll
      for (int reg = 0; reg < 16; reg++) {
        const int row = rb0 + (reg & 3) + 8 * (reg >> 2);
        C[(size_t)row * HH + col] = acc[mi][nj][reg] + bv;
      }
    }
}

// ---------------- WKV: chunk-parallel scan over T ----------------
__global__ __launch_bounds__(256) void wkv_part(const unsigned short* __restrict__ k,
    const unsigned short* __restrict__ v, const float* __restrict__ tdec,
    float* __restrict__ pnum, float* __restrict__ pden) {
  const int gid = blockIdx.x * 256 + threadIdx.x;   // 0 .. CC*BB*HH-1
  const int h = gid & (HH - 1);
  const int bh = gid & (BB * HH - 1);
  const int b = (gid >> 10) & (BB - 1);
  const int c = gid >> 13;
  const float td = __expf(-__expf(tdec[h]));
  size_t idx = (size_t)b * TT * HH + (size_t)(c * LL) * HH + h;
  float num = 0.f, den = 0.f;
#pragma unroll 8
  for (int i = 0; i < LL; ++i, idx += HH) {
    const float ek = __expf(bf2f(k[idx]));
    const float vt = bf2f(v[idx]);
    num = td * num + ek * vt;
    den = td * den + ek;
  }
  pnum[(size_t)c * (BB * HH) + bh] = num;
  pden[(size_t)c * (BB * HH) + bh] = den;
}

__global__ __launch_bounds__(256) void wkv_scan(const float* __restrict__ tdec,
    float* __restrict__ pnum, float* __restrict__ pden) {
  const int bh = blockIdx.x * 256 + threadIdx.x;     // 0..8191
  const int h = bh & (HH - 1);
  const float ed = __expf(tdec[h]);
  const float tdL = __expf(-ed * (float)LL);         // td^LL exactly
  float num = 0.f, den = 0.f;
#pragma unroll 8
  for (int c = 0; c < CC; ++c) {
    const size_t o = (size_t)c * (BB * HH) + bh;
    const float tn = pnum[o], td_ = pden[o];
    pnum[o] = num; pden[o] = den;
    num = tdL * num + tn;
    den = tdL * den + td_;
  }
}

__global__ __launch_bounds__(256) void wkv_final(const unsigned short* __restrict__ k,
    const unsigned short* __restrict__ v, const unsigned short* __restrict__ r,
    const float* __restrict__ tdec, const float* __restrict__ tfst,
    const float* __restrict__ pnum, const float* __restrict__ pden,
    unsigned short* __restrict__ rwkv) {
  const int gid = blockIdx.x * 256 + threadIdx.x;
  const int h = gid & (HH - 1);
  const int bh = gid & (BB * HH - 1);
  const int b = (gid >> 10) & (BB - 1);
  const int c = gid >> 13;
  const float td = __expf(-__expf(tdec[h]));
  const float etf = __expf(tfst[h]);
  float num = pnum[(size_t)c * (BB * HH) + bh];
  float den = pden[(size_t)c * (BB * HH) + bh];
  size_t idx = (size_t)b * TT * HH + (size_t)(c * LL) * HH + h;
#pragma unroll 4
  for (int i = 0; i < LL; ++i, idx += HH) {
    const float ek = __expf(bf2f(k[idx]));
    const float vt = bf2f(v[idx]);
    const float rt = bf2f(r[idx]);
    const float e = ek * etf;                        // exp(tf + k) = exp(k)*exp(tf)
    const float inv = __builtin_amdgcn_rcpf(den + e);
    const float outv = (num + e * vt) * inv;
    num = td * num + ek * vt;
    den = td * den + ek;
    rwkv[idx] = f2bf(outv * rt);
  }
}

extern "C" void kernel_launch(void* const* d_in, const int* in_sizes, int n_in,
                              void* d_out, int out_size, void* d_ws, size_t ws_size,
                              hipStream_t stream) {
  (void)in_sizes; (void)n_in; (void)out_size; (void)ws_size;
  const float* x    = (const float*)d_in[0];
  const float* tdec = (const float*)d_in[1];
  const float* tfst = (const float*)d_in[2];
  const float* tmk  = (const float*)d_in[3];
  const float* tmv  = (const float*)d_in[4];
  const float* tmr  = (const float*)d_in[5];
  const float* Wk   = (const float*)d_in[6];
  const float* Wv   = (const float*)d_in[7];
  const float* Wr   = (const float*)d_in[8];
  const float* Wo   = (const float*)d_in[9];
  const float* bo   = (const float*)d_in[10];
  float* out = (float*)d_out;

  char* ws = (char*)d_ws;
  const size_t MiB = (size_t)1 << 20;
  unsigned short* Wbf = (unsigned short*)(ws);             //   8 MiB
  unsigned short* kin = (unsigned short*)(ws + 8 * MiB);   //  32 MiB
  unsigned short* vin = (unsigned short*)(ws + 40 * MiB);  //  32 MiB
  unsigned short* rin = (unsigned short*)(ws + 72 * MiB);  //  32 MiB
  unsigned short* rb  = (unsigned short*)(ws + 104 * MiB); //  32 MiB  (peak 136 MiB)
  // k,v bf16 staged in d_out (64 MiB fp32 buffer = 2 x 32 MiB bf16); dead before gemm_o writes.
  unsigned short* kb = (unsigned short*)out;
  unsigned short* vb = kb + (size_t)MM * HH;
  unsigned short* rwkv = kin;                  // kin dead after gemm_kvr
  float* pnum = (float*)(ws + 40 * MiB);       // vin dead after gemm_kvr (2 MiB)
  float* pden = (float*)(ws + 42 * MiB);       // (2 MiB)

  hipLaunchKernelGGL(conv_w, dim3(1024, 4), dim3(256), 0, stream, Wk, Wv, Wr, Wo, Wbf);
  hipLaunchKernelGGL(mix_kernel, dim3(16384), dim3(256), 0, stream,
                     x, tmk, tmv, tmr, kin, vin, rin);
  hipLaunchKernelGGL(gemm_kvr, dim3(1024, 3), dim3(256), 0, stream,
                     kin, vin, rin, Wbf, kb, vb, rb);
  hipLaunchKernelGGL(wkv_part, dim3(2048), dim3(256), 0, stream,
                     kb, vb, tdec, pnum, pden);
  hipLaunchKernelGGL(wkv_scan, dim3(32), dim3(256), 0, stream,
                     tdec, pnum, pden);
  hipLaunchKernelGGL(wkv_final, dim3(2048), dim3(256), 0, stream,
                     kb, vb, rb, tdec, tfst, pnum, pden, rwkv);
  hipLaunchKernelGGL(gemm_o, dim3(1024), dim3(256), 0, stream,
                     rwkv, Wbf + (size_t)3 * HH * HH, bo, out);
}